// Round 1
// baseline (702.525 us; speedup 1.0000x reference)
//
#include <hip/hip_runtime.h>
#include <hip/hip_bf16.h>
#include <math.h>

#define N_NODES 20000
#define N_EDGES 320000
#define N_EDGES_SL (N_EDGES + N_NODES)
#define NB 32
#define NH 4
#define NC 64
#define HC 256   // NH*NC

// ---------------- concat: x0[n, 0:2]=pos, x0[n, 2:64]=x ----------------
__global__ void concat_kernel(const float* __restrict__ x, const float* __restrict__ pos,
                              float* __restrict__ x0) {
    int i = blockIdx.x * blockDim.x + threadIdx.x;
    if (i >= N_NODES * 64) return;
    int n = i >> 6, j = i & 63;
    x0[i] = (j < 2) ? pos[n * 2 + j] : x[n * 62 + (j - 2)];
}

// ---------------- CSR build ----------------
__global__ void hist_kernel(const int* __restrict__ ei, int* __restrict__ counts) {
    int i = blockIdx.x * blockDim.x + threadIdx.x;
    if (i >= N_EDGES_SL) return;
    int dst = (i < N_EDGES) ? ei[N_EDGES + i] : (i - N_EDGES);
    atomicAdd(&counts[dst], 1);
}

__global__ void scan_kernel(const int* __restrict__ counts, int* __restrict__ rowptr) {
    __shared__ int sm[256];
    __shared__ int carry;
    int tid = threadIdx.x;
    if (tid == 0) carry = 0;
    __syncthreads();
    for (int base = 0; base < N_NODES; base += 256) {
        int i = base + tid;
        int v = (i < N_NODES) ? counts[i] : 0;
        sm[tid] = v;
        __syncthreads();
        for (int off = 1; off < 256; off <<= 1) {
            int t = (tid >= off) ? sm[tid - off] : 0;
            __syncthreads();
            sm[tid] += t;
            __syncthreads();
        }
        int incl = sm[tid];
        int excl = incl - v;
        if (i < N_NODES) rowptr[i] = carry + excl;
        __syncthreads();
        if (tid == 255) carry += incl;
        __syncthreads();
    }
    if (tid == 0) rowptr[N_NODES] = carry;
}

__global__ void fill_kernel(const int* __restrict__ ei, const int* __restrict__ rowptr,
                            int* __restrict__ fillc, int* __restrict__ srclist) {
    int i = blockIdx.x * blockDim.x + threadIdx.x;
    if (i >= N_EDGES_SL) return;
    int src, dst;
    if (i < N_EDGES) { src = ei[i]; dst = ei[N_EDGES + i]; }
    else             { src = i - N_EDGES; dst = src; }
    int slot = rowptr[dst] + atomicAdd(&fillc[dst], 1);
    srclist[slot] = src;
}

// ---------------- simple fp32 tiled GEMM: C = A[M,K] @ B[K,Nc] ----------------
// block = 256 threads, 64x64 output tile, 4x4 per thread, BK=16
__global__ __launch_bounds__(256) void gemm_kernel(const float* __restrict__ A,
                                                   const float* __restrict__ Bw,
                                                   float* __restrict__ C,
                                                   int M, int K, int Nc) {
    __shared__ float As[16][65];
    __shared__ float Bs[16][65];
    int tid = threadIdx.x;
    int tx = tid & 15, ty = tid >> 4;
    int row0 = blockIdx.y * 64, col0 = blockIdx.x * 64;
    float acc[4][4];
#pragma unroll
    for (int i = 0; i < 4; ++i)
#pragma unroll
        for (int j = 0; j < 4; ++j) acc[i][j] = 0.f;

    for (int k0 = 0; k0 < K; k0 += 16) {
        // A tile: 64 rows x 16 k ; thread -> (m = tid/4, 4 consecutive k)
        int m = tid >> 2, kb = (tid & 3) * 4;
        float4 av = make_float4(0.f, 0.f, 0.f, 0.f);
        if (row0 + m < M) av = *(const float4*)&A[(size_t)(row0 + m) * K + k0 + kb];
        As[kb + 0][m] = av.x; As[kb + 1][m] = av.y; As[kb + 2][m] = av.z; As[kb + 3][m] = av.w;
        // B tile: 16 k x 64 cols ; thread -> (kk = tid/16, 4 consecutive cols)
        int kk = tid >> 4, cb = (tid & 15) * 4;
        float4 bv = *(const float4*)&Bw[(size_t)(k0 + kk) * Nc + col0 + cb];
        Bs[kk][cb + 0] = bv.x; Bs[kk][cb + 1] = bv.y; Bs[kk][cb + 2] = bv.z; Bs[kk][cb + 3] = bv.w;
        __syncthreads();
#pragma unroll
        for (int k = 0; k < 16; ++k) {
            float a[4], b[4];
#pragma unroll
            for (int i = 0; i < 4; ++i) a[i] = As[k][ty * 4 + i];
#pragma unroll
            for (int j = 0; j < 4; ++j) b[j] = Bs[k][tx * 4 + j];
#pragma unroll
            for (int i = 0; i < 4; ++i)
#pragma unroll
                for (int j = 0; j < 4; ++j) acc[i][j] += a[i] * b[j];
        }
        __syncthreads();
    }
#pragma unroll
    for (int i = 0; i < 4; ++i) {
        int r = row0 + ty * 4 + i;
        if (r < M) {
#pragma unroll
            for (int j = 0; j < 4; ++j)
                C[(size_t)r * Nc + col0 + tx * 4 + j] = acc[i][j];
        }
    }
}

// ---------------- per-node-head attention dots: as/ad[n,h] = sum_c h[n,h,c]*a[h,c] ----------------
__global__ __launch_bounds__(256) void alpha_kernel(const float* __restrict__ h,
                                                    const float* __restrict__ a_src,
                                                    const float* __restrict__ a_dst,
                                                    float* __restrict__ as_out,
                                                    float* __restrict__ ad_out) {
    int gw = (blockIdx.x * blockDim.x + threadIdx.x) >> 6;
    int lane = threadIdx.x & 63;
    if (gw >= N_NODES * NH) return;
    int n = gw >> 2, hh = gw & 3;
    float hv = h[(size_t)n * HC + hh * NC + lane];
    float s1 = hv * a_src[hh * NC + lane];
    float s2 = hv * a_dst[hh * NC + lane];
#pragma unroll
    for (int off = 32; off; off >>= 1) {
        s1 += __shfl_down(s1, off);
        s2 += __shfl_down(s2, off);
    }
    if (lane == 0) { as_out[n * NH + hh] = s1; ad_out[n * NH + hh] = s2; }
}

// ---------------- edge-softmax aggregation (online softmax), one wave per (node, head) ----------------
__global__ __launch_bounds__(256) void agg_kernel(const float* __restrict__ h,
                                                  const float* __restrict__ as_in,
                                                  const float* __restrict__ ad_in,
                                                  const int* __restrict__ rowptr,
                                                  const int* __restrict__ srclist,
                                                  const float* __restrict__ bias,
                                                  float* __restrict__ out) {
    int n = blockIdx.x;
    int hh = threadIdx.x >> 6, lane = threadIdx.x & 63;
    int start = rowptr[n], end = rowptr[n + 1];
    float adv = ad_in[n * NH + hh];
    float m = -INFINITY, den = 0.f, acc = 0.f;
    for (int j = start; j < end; ++j) {
        int s = srclist[j];
        float e = as_in[s * NH + hh] + adv;
        e = (e > 0.f) ? e : 0.2f * e;
        float mn = fmaxf(m, e);
        float scale = expf(m - mn);
        float p = expf(e - mn);
        den = den * scale + p;
        acc = acc * scale + p * h[(size_t)s * HC + hh * NC + lane];
        m = mn;
    }
    out[(size_t)n * HC + hh * NC + lane] = acc / (den + 1e-16f) + bias[hh * NC + lane];
}

// ---------------- global mean pool (atomic accumulate) ----------------
__global__ void pool_kernel(const float* __restrict__ o2, const int* __restrict__ batch,
                            float* __restrict__ pool, int* __restrict__ gcnt) {
    int n = blockIdx.x;
    int c = threadIdx.x;
    int b = batch[n];
    atomicAdd(&pool[b * HC + c], o2[(size_t)n * HC + c]);
    if (c == 0) atomicAdd(&gcnt[b], 1);
}

// ---------------- MLP tail: relu(relu(mean @ lw1 + lb1) @ lw2 + lb2) ----------------
__global__ __launch_bounds__(128) void tail_kernel(const float* __restrict__ pool,
                                                   const int* __restrict__ gcnt,
                                                   const float* __restrict__ lw1,
                                                   const float* __restrict__ lb1,
                                                   const float* __restrict__ lw2,
                                                   const float* __restrict__ lb2,
                                                   float* __restrict__ out) {
    __shared__ float pm[HC];
    __shared__ float hid[128];
    int b = blockIdx.x, t = threadIdx.x;
    int cnt = gcnt[b];
    float inv = 1.0f / (float)max(cnt, 1);
    pm[t] = pool[b * HC + t] * inv;
    pm[t + 128] = pool[b * HC + t + 128] * inv;
    __syncthreads();
    float s = lb1[t];
    for (int c = 0; c < HC; ++c) s += pm[c] * lw1[c * 128 + t];
    hid[t] = fmaxf(s, 0.f);
    __syncthreads();
    if (t < 10) {
        float s2 = lb2[t];
        for (int k = 0; k < 128; ++k) s2 += hid[k] * lw2[k * 10 + t];
        out[b * 10 + t] = fmaxf(s2, 0.f);
    }
}

extern "C" void kernel_launch(void* const* d_in, const int* in_sizes, int n_in,
                              void* d_out, int out_size, void* d_ws, size_t ws_size,
                              hipStream_t stream) {
    const float* x      = (const float*)d_in[0];
    const float* pos    = (const float*)d_in[1];
    const int*   ei     = (const int*)d_in[2];
    const int*   batch  = (const int*)d_in[3];
    const float* W1     = (const float*)d_in[4];
    const float* a_src1 = (const float*)d_in[5];
    const float* a_dst1 = (const float*)d_in[6];
    const float* b1     = (const float*)d_in[7];
    const float* W2     = (const float*)d_in[8];
    const float* a_src2 = (const float*)d_in[9];
    const float* a_dst2 = (const float*)d_in[10];
    const float* b2     = (const float*)d_in[11];
    const float* lw1    = (const float*)d_in[12];
    const float* lb1    = (const float*)d_in[13];
    const float* lw2    = (const float*)d_in[14];
    const float* lb2    = (const float*)d_in[15];
    float* out = (float*)d_out;

    char* ws = (char*)d_ws;
    size_t off = 0;
    auto alloc = [&](size_t bytes) -> void* {
        void* p = ws + off;
        off = (off + bytes + 255) & ~(size_t)255;
        return p;
    };
    // zero-init region first (contiguous): counts, fillc, gcnt, pool
    int*   counts  = (int*)alloc(N_NODES * 4);
    int*   fillc   = (int*)alloc(N_NODES * 4);
    int*   gcnt    = (int*)alloc(NB * 4);
    float* poolbuf = (float*)alloc(NB * HC * 4);
    size_t zero_bytes = off;
    int*   rowptr  = (int*)alloc((N_NODES + 1) * 4);
    int*   srclist = (int*)alloc((size_t)N_EDGES_SL * 4);
    float* x0      = (float*)alloc((size_t)N_NODES * 64 * 4);
    float* hbuf    = (float*)alloc((size_t)N_NODES * HC * 4);
    float* o1      = (float*)alloc((size_t)N_NODES * HC * 4);  // also reused as o2
    float* asb     = (float*)alloc((size_t)N_NODES * NH * 4);
    float* adb     = (float*)alloc((size_t)N_NODES * NH * 4);
    float* o2 = o1;

    hipMemsetAsync(d_ws, 0, zero_bytes, stream);

    concat_kernel<<<(N_NODES * 64 + 255) / 256, 256, 0, stream>>>(x, pos, x0);
    hist_kernel<<<(N_EDGES_SL + 255) / 256, 256, 0, stream>>>(ei, counts);
    scan_kernel<<<1, 256, 0, stream>>>(counts, rowptr);
    fill_kernel<<<(N_EDGES_SL + 255) / 256, 256, 0, stream>>>(ei, rowptr, fillc, srclist);

    dim3 ggrid(HC / 64, (N_NODES + 63) / 64);
    // ---- layer 1 ----
    gemm_kernel<<<ggrid, 256, 0, stream>>>(x0, W1, hbuf, N_NODES, 64, HC);
    alpha_kernel<<<(N_NODES * NH * 64 + 255) / 256, 256, 0, stream>>>(hbuf, a_src1, a_dst1, asb, adb);
    agg_kernel<<<N_NODES, 256, 0, stream>>>(hbuf, asb, adb, rowptr, srclist, b1, o1);
    // ---- layer 2 ----
    gemm_kernel<<<ggrid, 256, 0, stream>>>(o1, W2, hbuf, N_NODES, HC, HC);
    alpha_kernel<<<(N_NODES * NH * 64 + 255) / 256, 256, 0, stream>>>(hbuf, a_src2, a_dst2, asb, adb);
    agg_kernel<<<N_NODES, 256, 0, stream>>>(hbuf, asb, adb, rowptr, srclist, b2, o2);
    // ---- pool + tail ----
    pool_kernel<<<N_NODES, HC, 0, stream>>>(o2, batch, poolbuf, gcnt);
    tail_kernel<<<NB, 128, 0, stream>>>(poolbuf, gcnt, lw1, lb1, lw2, lb2, out);
}

// Round 2
// 481.555 us; speedup vs baseline: 1.4589x; 1.4589x over previous
//
#include <hip/hip_runtime.h>
#include <hip/hip_bf16.h>
#include <math.h>

#define N_NODES 20000
#define N_EDGES 320000
#define N_EDGES_SL (N_EDGES + N_NODES)
#define NB 32
#define NH 4
#define NC 64
#define HC 256   // NH*NC
#define SCAN_BLOCKS ((N_NODES + 255) / 256)

// ---------------- concat: x0[n, 0:2]=pos, x0[n, 2:64]=x ----------------
__global__ void concat_kernel(const float* __restrict__ x, const float* __restrict__ pos,
                              float* __restrict__ x0) {
    int i = blockIdx.x * blockDim.x + threadIdx.x;
    if (i >= N_NODES * 64) return;
    int n = i >> 6, j = i & 63;
    x0[i] = (j < 2) ? pos[n * 2 + j] : x[n * 62 + (j - 2)];
}

// ---------------- CSR build ----------------
__global__ void hist_kernel(const int* __restrict__ ei, int* __restrict__ counts) {
    int i = blockIdx.x * blockDim.x + threadIdx.x;
    if (i >= N_EDGES_SL) return;
    int dst = (i < N_EDGES) ? ei[N_EDGES + i] : (i - N_EDGES);
    atomicAdd(&counts[dst], 1);
}

// multi-block exclusive scan of counts -> rowptr
__global__ void scan_block_kernel(const int* __restrict__ counts, int* __restrict__ rowptr,
                                  int* __restrict__ bsums) {
    __shared__ int sm[256];
    int tid = threadIdx.x, blk = blockIdx.x;
    int i = blk * 256 + tid;
    int v = (i < N_NODES) ? counts[i] : 0;
    sm[tid] = v;
    __syncthreads();
#pragma unroll
    for (int off = 1; off < 256; off <<= 1) {
        int t = (tid >= off) ? sm[tid - off] : 0;
        __syncthreads();
        sm[tid] += t;
        __syncthreads();
    }
    if (i < N_NODES) rowptr[i] = sm[tid] - v;   // exclusive within block
    if (tid == 255) bsums[blk] = sm[255];
}

__global__ void scan_sums_kernel(int* __restrict__ bsums, int* __restrict__ rowptr) {
    __shared__ int sm[128];
    int tid = threadIdx.x;
    int v = (tid < SCAN_BLOCKS) ? bsums[tid] : 0;
    sm[tid] = v;
    __syncthreads();
#pragma unroll
    for (int off = 1; off < 128; off <<= 1) {
        int t = (tid >= off) ? sm[tid - off] : 0;
        __syncthreads();
        sm[tid] += t;
        __syncthreads();
    }
    if (tid < SCAN_BLOCKS) bsums[tid] = sm[tid] - v;  // exclusive
    if (tid == 127) rowptr[N_NODES] = sm[127];        // total
}

__global__ void scan_add_kernel(const int* __restrict__ bsums, int* __restrict__ rowptr) {
    int i = blockIdx.x * blockDim.x + threadIdx.x;
    if (i < N_NODES) rowptr[i] += bsums[blockIdx.x];
}

__global__ void fill_kernel(const int* __restrict__ ei, const int* __restrict__ rowptr,
                            int* __restrict__ fillc, int* __restrict__ srclist) {
    int i = blockIdx.x * blockDim.x + threadIdx.x;
    if (i >= N_EDGES_SL) return;
    int src, dst;
    if (i < N_EDGES) { src = ei[i]; dst = ei[N_EDGES + i]; }
    else             { src = i - N_EDGES; dst = src; }
    int slot = rowptr[dst] + atomicAdd(&fillc[dst], 1);
    srclist[slot] = src;
}

// ---------------- simple fp32 tiled GEMM: C = A[M,K] @ B[K,Nc] ----------------
__global__ __launch_bounds__(256) void gemm_kernel(const float* __restrict__ A,
                                                   const float* __restrict__ Bw,
                                                   float* __restrict__ C,
                                                   int M, int K, int Nc) {
    __shared__ float As[16][65];
    __shared__ float Bs[16][65];
    int tid = threadIdx.x;
    int tx = tid & 15, ty = tid >> 4;
    int row0 = blockIdx.y * 64, col0 = blockIdx.x * 64;
    float acc[4][4];
#pragma unroll
    for (int i = 0; i < 4; ++i)
#pragma unroll
        for (int j = 0; j < 4; ++j) acc[i][j] = 0.f;

    for (int k0 = 0; k0 < K; k0 += 16) {
        int m = tid >> 2, kb = (tid & 3) * 4;
        float4 av = make_float4(0.f, 0.f, 0.f, 0.f);
        if (row0 + m < M) av = *(const float4*)&A[(size_t)(row0 + m) * K + k0 + kb];
        As[kb + 0][m] = av.x; As[kb + 1][m] = av.y; As[kb + 2][m] = av.z; As[kb + 3][m] = av.w;
        int kk = tid >> 4, cb = (tid & 15) * 4;
        float4 bv = *(const float4*)&Bw[(size_t)(k0 + kk) * Nc + col0 + cb];
        Bs[kk][cb + 0] = bv.x; Bs[kk][cb + 1] = bv.y; Bs[kk][cb + 2] = bv.z; Bs[kk][cb + 3] = bv.w;
        __syncthreads();
#pragma unroll
        for (int k = 0; k < 16; ++k) {
            float a[4], b[4];
#pragma unroll
            for (int i = 0; i < 4; ++i) a[i] = As[k][ty * 4 + i];
#pragma unroll
            for (int j = 0; j < 4; ++j) b[j] = Bs[k][tx * 4 + j];
#pragma unroll
            for (int i = 0; i < 4; ++i)
#pragma unroll
                for (int j = 0; j < 4; ++j) acc[i][j] += a[i] * b[j];
        }
        __syncthreads();
    }
#pragma unroll
    for (int i = 0; i < 4; ++i) {
        int r = row0 + ty * 4 + i;
        if (r < M) {
#pragma unroll
            for (int j = 0; j < 4; ++j)
                C[(size_t)r * Nc + col0 + tx * 4 + j] = acc[i][j];
        }
    }
}

// ---------------- per-node-head attention dots ----------------
__global__ __launch_bounds__(256) void alpha_kernel(const float* __restrict__ h,
                                                    const float* __restrict__ a_src,
                                                    const float* __restrict__ a_dst,
                                                    float* __restrict__ as_out,
                                                    float* __restrict__ ad_out) {
    int gw = (blockIdx.x * blockDim.x + threadIdx.x) >> 6;
    int lane = threadIdx.x & 63;
    if (gw >= N_NODES * NH) return;
    int n = gw >> 2, hh = gw & 3;
    float hv = h[(size_t)n * HC + hh * NC + lane];
    float s1 = hv * a_src[hh * NC + lane];
    float s2 = hv * a_dst[hh * NC + lane];
#pragma unroll
    for (int off = 32; off; off >>= 1) {
        s1 += __shfl_down(s1, off);
        s2 += __shfl_down(s2, off);
    }
    if (lane == 0) { as_out[n * NH + hh] = s1; ad_out[n * NH + hh] = s2; }
}

// ---------------- edge-softmax aggregation (online softmax), one wave per (node, head) ----------------
__global__ __launch_bounds__(256) void agg_kernel(const float* __restrict__ h,
                                                  const float* __restrict__ as_in,
                                                  const float* __restrict__ ad_in,
                                                  const int* __restrict__ rowptr,
                                                  const int* __restrict__ srclist,
                                                  const float* __restrict__ bias,
                                                  float* __restrict__ out) {
    int n = blockIdx.x;
    int hh = threadIdx.x >> 6, lane = threadIdx.x & 63;
    int start = rowptr[n], end = rowptr[n + 1];
    float adv = ad_in[n * NH + hh];
    float m = -INFINITY, den = 0.f, acc = 0.f;
    for (int j = start; j < end; ++j) {
        int s = srclist[j];
        float e = as_in[s * NH + hh] + adv;
        e = (e > 0.f) ? e : 0.2f * e;
        float mn = fmaxf(m, e);
        float scale = expf(m - mn);
        float p = expf(e - mn);
        den = den * scale + p;
        acc = acc * scale + p * h[(size_t)s * HC + hh * NC + lane];
        m = mn;
    }
    out[(size_t)n * HC + hh * NC + lane] = acc / (den + 1e-16f) + bias[hh * NC + lane];
}

// ---------------- graph boundaries: gstart[b] = lower_bound(batch, b) ----------------
__global__ void gbound_kernel(const int* __restrict__ batch, int* __restrict__ gstart) {
    int t = threadIdx.x;
    if (t > NB) return;
    int lo = 0, hi = N_NODES;
    while (lo < hi) {
        int mid = (lo + hi) >> 1;
        if (batch[mid] < t) lo = mid + 1; else hi = mid;
    }
    gstart[t] = lo;
}

// ---------------- mean pool: one block per graph, no atomics ----------------
__global__ __launch_bounds__(256) void gpool_kernel(const float* __restrict__ o2,
                                                    const int* __restrict__ gstart,
                                                    float* __restrict__ mean) {
    int b = blockIdx.x, c = threadIdx.x;
    int s = gstart[b], e = gstart[b + 1];
    int cnt = e - s;
    float s0 = 0.f, s1 = 0.f, s2 = 0.f, s3 = 0.f;
    int n = s;
    for (; n + 3 < e; n += 4) {
        s0 += o2[(size_t)(n + 0) * HC + c];
        s1 += o2[(size_t)(n + 1) * HC + c];
        s2 += o2[(size_t)(n + 2) * HC + c];
        s3 += o2[(size_t)(n + 3) * HC + c];
    }
    for (; n < e; ++n) s0 += o2[(size_t)n * HC + c];
    float inv = 1.0f / (float)max(cnt, 1);
    mean[b * HC + c] = (s0 + s1 + s2 + s3) * inv;
}

// ---------------- MLP tail ----------------
__global__ __launch_bounds__(128) void tail_kernel(const float* __restrict__ mean,
                                                   const float* __restrict__ lw1,
                                                   const float* __restrict__ lb1,
                                                   const float* __restrict__ lw2,
                                                   const float* __restrict__ lb2,
                                                   float* __restrict__ out) {
    __shared__ float pm[HC];
    __shared__ float hid[128];
    int b = blockIdx.x, t = threadIdx.x;
    pm[t] = mean[b * HC + t];
    pm[t + 128] = mean[b * HC + t + 128];
    __syncthreads();
    float s = lb1[t];
    for (int c = 0; c < HC; ++c) s += pm[c] * lw1[c * 128 + t];
    hid[t] = fmaxf(s, 0.f);
    __syncthreads();
    if (t < 10) {
        float s2 = lb2[t];
        for (int k = 0; k < 128; ++k) s2 += hid[k] * lw2[k * 10 + t];
        out[b * 10 + t] = fmaxf(s2, 0.f);
    }
}

extern "C" void kernel_launch(void* const* d_in, const int* in_sizes, int n_in,
                              void* d_out, int out_size, void* d_ws, size_t ws_size,
                              hipStream_t stream) {
    const float* x      = (const float*)d_in[0];
    const float* pos    = (const float*)d_in[1];
    const int*   ei     = (const int*)d_in[2];
    const int*   batch  = (const int*)d_in[3];
    const float* W1     = (const float*)d_in[4];
    const float* a_src1 = (const float*)d_in[5];
    const float* a_dst1 = (const float*)d_in[6];
    const float* b1     = (const float*)d_in[7];
    const float* W2     = (const float*)d_in[8];
    const float* a_src2 = (const float*)d_in[9];
    const float* a_dst2 = (const float*)d_in[10];
    const float* b2     = (const float*)d_in[11];
    const float* lw1    = (const float*)d_in[12];
    const float* lb1    = (const float*)d_in[13];
    const float* lw2    = (const float*)d_in[14];
    const float* lb2    = (const float*)d_in[15];
    float* out = (float*)d_out;

    char* ws = (char*)d_ws;
    size_t off = 0;
    auto alloc = [&](size_t bytes) -> void* {
        void* p = ws + off;
        off = (off + bytes + 255) & ~(size_t)255;
        return p;
    };
    // zero-init region first (contiguous): counts, fillc
    int*   counts  = (int*)alloc(N_NODES * 4);
    int*   fillc   = (int*)alloc(N_NODES * 4);
    size_t zero_bytes = off;
    int*   rowptr  = (int*)alloc((N_NODES + 1) * 4);
    int*   bsums   = (int*)alloc(SCAN_BLOCKS * 4);
    int*   srclist = (int*)alloc((size_t)N_EDGES_SL * 4);
    int*   gstart  = (int*)alloc((NB + 1) * 4);
    float* x0      = (float*)alloc((size_t)N_NODES * 64 * 4);
    float* hbuf    = (float*)alloc((size_t)N_NODES * HC * 4);
    float* o1      = (float*)alloc((size_t)N_NODES * HC * 4);  // reused as o2
    float* asb     = (float*)alloc((size_t)N_NODES * NH * 4);
    float* adb     = (float*)alloc((size_t)N_NODES * NH * 4);
    float* meanb   = (float*)alloc(NB * HC * 4);
    float* o2 = o1;

    hipMemsetAsync(d_ws, 0, zero_bytes, stream);

    concat_kernel<<<(N_NODES * 64 + 255) / 256, 256, 0, stream>>>(x, pos, x0);
    hist_kernel<<<(N_EDGES_SL + 255) / 256, 256, 0, stream>>>(ei, counts);
    scan_block_kernel<<<SCAN_BLOCKS, 256, 0, stream>>>(counts, rowptr, bsums);
    scan_sums_kernel<<<1, 128, 0, stream>>>(bsums, rowptr);
    scan_add_kernel<<<SCAN_BLOCKS, 256, 0, stream>>>(bsums, rowptr);
    fill_kernel<<<(N_EDGES_SL + 255) / 256, 256, 0, stream>>>(ei, rowptr, fillc, srclist);
    gbound_kernel<<<1, 64, 0, stream>>>(batch, gstart);

    dim3 ggrid(HC / 64, (N_NODES + 63) / 64);
    // ---- layer 1 ----
    gemm_kernel<<<ggrid, 256, 0, stream>>>(x0, W1, hbuf, N_NODES, 64, HC);
    alpha_kernel<<<(N_NODES * NH * 64 + 255) / 256, 256, 0, stream>>>(hbuf, a_src1, a_dst1, asb, adb);
    agg_kernel<<<N_NODES, 256, 0, stream>>>(hbuf, asb, adb, rowptr, srclist, b1, o1);
    // ---- layer 2 ----
    gemm_kernel<<<ggrid, 256, 0, stream>>>(o1, W2, hbuf, N_NODES, HC, HC);
    alpha_kernel<<<(N_NODES * NH * 64 + 255) / 256, 256, 0, stream>>>(hbuf, a_src2, a_dst2, asb, adb);
    agg_kernel<<<N_NODES, 256, 0, stream>>>(hbuf, asb, adb, rowptr, srclist, b2, o2);
    // ---- pool + tail ----
    gpool_kernel<<<NB, HC, 0, stream>>>(o2, gstart, meanb);
    tail_kernel<<<NB, 128, 0, stream>>>(meanb, lw1, lb1, lw2, lb2, out);
}

// Round 3
// 408.057 us; speedup vs baseline: 1.7216x; 1.1801x over previous
//
#include <hip/hip_runtime.h>
#include <hip/hip_bf16.h>
#include <math.h>

#define N_NODES 20000
#define N_EDGES 320000
#define N_EDGES_SL (N_EDGES + N_NODES)
#define NB 32
#define NH 4
#define NC 64
#define HC 256   // NH*NC
#define SCAN_BLOCKS ((N_NODES + 255) / 256)

// ---------------- concat: x0[n, 0:2]=pos, x0[n, 2:64]=x ----------------
__global__ void concat_kernel(const float* __restrict__ x, const float* __restrict__ pos,
                              float* __restrict__ x0) {
    int i = blockIdx.x * blockDim.x + threadIdx.x;
    if (i >= N_NODES * 64) return;
    int n = i >> 6, j = i & 63;
    x0[i] = (j < 2) ? pos[n * 2 + j] : x[n * 62 + (j - 2)];
}

// ---------------- CSR build ----------------
__global__ void hist_kernel(const int* __restrict__ ei, int* __restrict__ counts) {
    int i = blockIdx.x * blockDim.x + threadIdx.x;
    if (i >= N_EDGES_SL) return;
    int dst = (i < N_EDGES) ? ei[N_EDGES + i] : (i - N_EDGES);
    atomicAdd(&counts[dst], 1);
}

__global__ void scan_block_kernel(const int* __restrict__ counts, int* __restrict__ rowptr,
                                  int* __restrict__ bsums) {
    __shared__ int sm[256];
    int tid = threadIdx.x, blk = blockIdx.x;
    int i = blk * 256 + tid;
    int v = (i < N_NODES) ? counts[i] : 0;
    sm[tid] = v;
    __syncthreads();
#pragma unroll
    for (int off = 1; off < 256; off <<= 1) {
        int t = (tid >= off) ? sm[tid - off] : 0;
        __syncthreads();
        sm[tid] += t;
        __syncthreads();
    }
    if (i < N_NODES) rowptr[i] = sm[tid] - v;   // exclusive within block
    if (tid == 255) bsums[blk] = sm[255];
}

__global__ void scan_sums_kernel(int* __restrict__ bsums, int* __restrict__ rowptr) {
    __shared__ int sm[128];
    int tid = threadIdx.x;
    int v = (tid < SCAN_BLOCKS) ? bsums[tid] : 0;
    sm[tid] = v;
    __syncthreads();
#pragma unroll
    for (int off = 1; off < 128; off <<= 1) {
        int t = (tid >= off) ? sm[tid - off] : 0;
        __syncthreads();
        sm[tid] += t;
        __syncthreads();
    }
    if (tid < SCAN_BLOCKS) bsums[tid] = sm[tid] - v;  // exclusive
    if (tid == 127) rowptr[N_NODES] = sm[127];        // total
}

__global__ void scan_add_kernel(const int* __restrict__ bsums, int* __restrict__ rowptr) {
    int i = blockIdx.x * blockDim.x + threadIdx.x;
    if (i < N_NODES) rowptr[i] += bsums[blockIdx.x];
}

__global__ void fill_kernel(const int* __restrict__ ei, const int* __restrict__ rowptr,
                            int* __restrict__ fillc, int* __restrict__ srclist) {
    int i = blockIdx.x * blockDim.x + threadIdx.x;
    if (i >= N_EDGES_SL) return;
    int src, dst;
    if (i < N_EDGES) { src = ei[i]; dst = ei[N_EDGES + i]; }
    else             { src = i - N_EDGES; dst = src; }
    int slot = rowptr[dst] + atomicAdd(&fillc[dst], 1);
    srclist[slot] = src;
}

// ---------------- fp32 GEMM: 128x128 tile, 8x8/thread, b128 LDS reads ----------------
#define BM 128
#define BN 128
#define BK 8
__global__ __launch_bounds__(256) void gemm_kernel(const float* __restrict__ A,
                                                   const float* __restrict__ Bw,
                                                   float* __restrict__ C,
                                                   int M, int K, int Nc) {
    __shared__ float As[BK][BM];
    __shared__ float Bs[BK][BN];
    int tid = threadIdx.x;
    int tx = tid & 15, ty = tid >> 4;           // 16x16 thread grid
    int row0 = blockIdx.y * BM, col0 = blockIdx.x * BN;
    float acc[8][8];
#pragma unroll
    for (int i = 0; i < 8; ++i)
#pragma unroll
        for (int j = 0; j < 8; ++j) acc[i][j] = 0.f;

    int arow = tid >> 1, acol = (tid & 1) * 4;  // A stage: 128 rows x 8 k
    int brow = tid >> 5, bcol = (tid & 31) * 4; // B stage: 8 k x 128 cols

    for (int k0 = 0; k0 < K; k0 += BK) {
        float4 av = make_float4(0.f, 0.f, 0.f, 0.f);
        if (row0 + arow < M) av = *(const float4*)&A[(size_t)(row0 + arow) * K + k0 + acol];
        As[acol + 0][arow] = av.x; As[acol + 1][arow] = av.y;
        As[acol + 2][arow] = av.z; As[acol + 3][arow] = av.w;
        float4 bv = *(const float4*)&Bw[(size_t)(k0 + brow) * Nc + col0 + bcol];
        *(float4*)&Bs[brow][bcol] = bv;
        __syncthreads();
#pragma unroll
        for (int k = 0; k < BK; ++k) {
            float a[8], b[8];
            *(float4*)&a[0] = *(const float4*)&As[k][ty * 4];
            *(float4*)&a[4] = *(const float4*)&As[k][64 + ty * 4];
            *(float4*)&b[0] = *(const float4*)&Bs[k][tx * 4];
            *(float4*)&b[4] = *(const float4*)&Bs[k][64 + tx * 4];
#pragma unroll
            for (int i = 0; i < 8; ++i)
#pragma unroll
                for (int j = 0; j < 8; ++j) acc[i][j] += a[i] * b[j];
        }
        __syncthreads();
    }
#pragma unroll
    for (int i = 0; i < 8; ++i) {
        int r = row0 + ((i < 4) ? (ty * 4 + i) : (64 + ty * 4 + (i - 4)));
        if (r < M) {
            *(float4*)&C[(size_t)r * Nc + col0 + tx * 4] =
                make_float4(acc[i][0], acc[i][1], acc[i][2], acc[i][3]);
            *(float4*)&C[(size_t)r * Nc + col0 + 64 + tx * 4] =
                make_float4(acc[i][4], acc[i][5], acc[i][6], acc[i][7]);
        }
    }
}

// ---------------- per-node-head attention dots ----------------
__global__ __launch_bounds__(256) void alpha_kernel(const float* __restrict__ h,
                                                    const float* __restrict__ a_src,
                                                    const float* __restrict__ a_dst,
                                                    float* __restrict__ as_out,
                                                    float* __restrict__ ad_out) {
    int gw = (blockIdx.x * blockDim.x + threadIdx.x) >> 6;
    int lane = threadIdx.x & 63;
    if (gw >= N_NODES * NH) return;
    int n = gw >> 2, hh = gw & 3;
    float hv = h[(size_t)n * HC + hh * NC + lane];
    float s1 = hv * a_src[hh * NC + lane];
    float s2 = hv * a_dst[hh * NC + lane];
#pragma unroll
    for (int off = 32; off; off >>= 1) {
        s1 += __shfl_down(s1, off);
        s2 += __shfl_down(s2, off);
    }
    if (lane == 0) { as_out[n * NH + hh] = s1; ad_out[n * NH + hh] = s2; }
}

// ---------------- softmax weights: one thread per (node, head) ----------------
__global__ __launch_bounds__(256) void wgt_kernel(const float* __restrict__ as_in,
                                                  const float* __restrict__ ad_in,
                                                  const int* __restrict__ rowptr,
                                                  const int* __restrict__ srclist,
                                                  float* __restrict__ w,
                                                  float* __restrict__ denb) {
    int t = blockIdx.x * blockDim.x + threadIdx.x;
    if (t >= N_NODES * NH) return;
    int n = t >> 2, hh = t & 3;
    int start = rowptr[n], end = rowptr[n + 1];
    float adv = ad_in[n * NH + hh];
    float m = -INFINITY;
#pragma unroll 4
    for (int j = start; j < end; ++j) {
        int s = srclist[j];
        float e = as_in[s * NH + hh] + adv;
        e = (e > 0.f) ? e : 0.2f * e;
        m = fmaxf(m, e);
    }
    float den = 0.f;
#pragma unroll 4
    for (int j = start; j < end; ++j) {
        int s = srclist[j];
        float e = as_in[s * NH + hh] + adv;
        e = (e > 0.f) ? e : 0.2f * e;
        float p = __expf(e - m);
        den += p;
        w[j * NH + hh] = p;
    }
    denb[t] = den;
}

// ---------------- weighted gather: one wave per node, lane = 4 channels ----------------
__global__ __launch_bounds__(256) void gather_kernel(const float* __restrict__ h,
                                                     const float* __restrict__ w,
                                                     const float* __restrict__ denb,
                                                     const int* __restrict__ rowptr,
                                                     const int* __restrict__ srclist,
                                                     const float* __restrict__ bias,
                                                     float* __restrict__ out) {
    int node = blockIdx.x * 4 + (threadIdx.x >> 6);
    int lane = threadIdx.x & 63;
    int hh = lane >> 4;
    if (node >= N_NODES) return;
    int start = rowptr[node], end = rowptr[node + 1];
    float4 acc = make_float4(0.f, 0.f, 0.f, 0.f);
#pragma unroll 2
    for (int j = start; j < end; ++j) {
        int s = srclist[j];
        float wv = w[j * NH + hh];
        float4 hv = *(const float4*)&h[(size_t)s * HC + lane * 4];
        acc.x += wv * hv.x; acc.y += wv * hv.y;
        acc.z += wv * hv.z; acc.w += wv * hv.w;
    }
    float inv = 1.0f / (denb[node * NH + hh] + 1e-16f);
    float4 bv = *(const float4*)&bias[lane * 4];
    float4 o;
    o.x = acc.x * inv + bv.x; o.y = acc.y * inv + bv.y;
    o.z = acc.z * inv + bv.z; o.w = acc.w * inv + bv.w;
    *(float4*)&out[(size_t)node * HC + lane * 4] = o;
}

// ---------------- graph boundaries ----------------
__global__ void gbound_kernel(const int* __restrict__ batch, int* __restrict__ gstart) {
    int t = threadIdx.x;
    if (t > NB) return;
    int lo = 0, hi = N_NODES;
    while (lo < hi) {
        int mid = (lo + hi) >> 1;
        if (batch[mid] < t) lo = mid + 1; else hi = mid;
    }
    gstart[t] = lo;
}

// ---------------- mean pool: one block per graph ----------------
__global__ __launch_bounds__(256) void gpool_kernel(const float* __restrict__ o2,
                                                    const int* __restrict__ gstart,
                                                    float* __restrict__ mean) {
    int b = blockIdx.x, c = threadIdx.x;
    int s = gstart[b], e = gstart[b + 1];
    int cnt = e - s;
    float s0 = 0.f, s1 = 0.f, s2 = 0.f, s3 = 0.f;
    int n = s;
    for (; n + 3 < e; n += 4) {
        s0 += o2[(size_t)(n + 0) * HC + c];
        s1 += o2[(size_t)(n + 1) * HC + c];
        s2 += o2[(size_t)(n + 2) * HC + c];
        s3 += o2[(size_t)(n + 3) * HC + c];
    }
    for (; n < e; ++n) s0 += o2[(size_t)n * HC + c];
    float inv = 1.0f / (float)max(cnt, 1);
    mean[b * HC + c] = (s0 + s1 + s2 + s3) * inv;
}

// ---------------- MLP tail ----------------
__global__ __launch_bounds__(128) void tail_kernel(const float* __restrict__ mean,
                                                   const float* __restrict__ lw1,
                                                   const float* __restrict__ lb1,
                                                   const float* __restrict__ lw2,
                                                   const float* __restrict__ lb2,
                                                   float* __restrict__ out) {
    __shared__ float pm[HC];
    __shared__ float hid[128];
    int b = blockIdx.x, t = threadIdx.x;
    pm[t] = mean[b * HC + t];
    pm[t + 128] = mean[b * HC + t + 128];
    __syncthreads();
    float s = lb1[t];
    for (int c = 0; c < HC; ++c) s += pm[c] * lw1[c * 128 + t];
    hid[t] = fmaxf(s, 0.f);
    __syncthreads();
    if (t < 10) {
        float s2 = lb2[t];
        for (int k = 0; k < 128; ++k) s2 += hid[k] * lw2[k * 10 + t];
        out[b * 10 + t] = fmaxf(s2, 0.f);
    }
}

extern "C" void kernel_launch(void* const* d_in, const int* in_sizes, int n_in,
                              void* d_out, int out_size, void* d_ws, size_t ws_size,
                              hipStream_t stream) {
    const float* x      = (const float*)d_in[0];
    const float* pos    = (const float*)d_in[1];
    const int*   ei     = (const int*)d_in[2];
    const int*   batch  = (const int*)d_in[3];
    const float* W1     = (const float*)d_in[4];
    const float* a_src1 = (const float*)d_in[5];
    const float* a_dst1 = (const float*)d_in[6];
    const float* b1     = (const float*)d_in[7];
    const float* W2     = (const float*)d_in[8];
    const float* a_src2 = (const float*)d_in[9];
    const float* a_dst2 = (const float*)d_in[10];
    const float* b2     = (const float*)d_in[11];
    const float* lw1    = (const float*)d_in[12];
    const float* lb1    = (const float*)d_in[13];
    const float* lw2    = (const float*)d_in[14];
    const float* lb2    = (const float*)d_in[15];
    float* out = (float*)d_out;

    char* ws = (char*)d_ws;
    size_t off = 0;
    auto alloc = [&](size_t bytes) -> void* {
        void* p = ws + off;
        off = (off + bytes + 255) & ~(size_t)255;
        return p;
    };
    int*   counts  = (int*)alloc(N_NODES * 4);
    int*   fillc   = (int*)alloc(N_NODES * 4);
    size_t zero_bytes = off;
    int*   rowptr  = (int*)alloc((N_NODES + 1) * 4);
    int*   bsums   = (int*)alloc(SCAN_BLOCKS * 4);
    int*   srclist = (int*)alloc((size_t)N_EDGES_SL * 4);
    int*   gstart  = (int*)alloc((NB + 1) * 4);
    float* x0      = (float*)alloc((size_t)N_NODES * 64 * 4);
    float* hbuf    = (float*)alloc((size_t)N_NODES * HC * 4);
    float* o1      = (float*)alloc((size_t)N_NODES * HC * 4);  // reused as o2
    float* asb     = (float*)alloc((size_t)N_NODES * NH * 4);
    float* adb     = (float*)alloc((size_t)N_NODES * NH * 4);
    float* wbuf    = (float*)alloc((size_t)N_EDGES_SL * NH * 4);
    float* denb    = (float*)alloc((size_t)N_NODES * NH * 4);
    float* meanb   = (float*)alloc(NB * HC * 4);
    float* o2 = o1;

    hipMemsetAsync(d_ws, 0, zero_bytes, stream);

    concat_kernel<<<(N_NODES * 64 + 255) / 256, 256, 0, stream>>>(x, pos, x0);
    hist_kernel<<<(N_EDGES_SL + 255) / 256, 256, 0, stream>>>(ei, counts);
    scan_block_kernel<<<SCAN_BLOCKS, 256, 0, stream>>>(counts, rowptr, bsums);
    scan_sums_kernel<<<1, 128, 0, stream>>>(bsums, rowptr);
    scan_add_kernel<<<SCAN_BLOCKS, 256, 0, stream>>>(bsums, rowptr);
    fill_kernel<<<(N_EDGES_SL + 255) / 256, 256, 0, stream>>>(ei, rowptr, fillc, srclist);
    gbound_kernel<<<1, 64, 0, stream>>>(batch, gstart);

    dim3 ggrid(HC / BN, (N_NODES + BM - 1) / BM);
    int ngrid = (N_NODES + 3) / 4;
    // ---- layer 1 ----
    gemm_kernel<<<ggrid, 256, 0, stream>>>(x0, W1, hbuf, N_NODES, 64, HC);
    alpha_kernel<<<(N_NODES * NH * 64 + 255) / 256, 256, 0, stream>>>(hbuf, a_src1, a_dst1, asb, adb);
    wgt_kernel<<<(N_NODES * NH + 255) / 256, 256, 0, stream>>>(asb, adb, rowptr, srclist, wbuf, denb);
    gather_kernel<<<ngrid, 256, 0, stream>>>(hbuf, wbuf, denb, rowptr, srclist, b1, o1);
    // ---- layer 2 ----
    gemm_kernel<<<ggrid, 256, 0, stream>>>(o1, W2, hbuf, N_NODES, HC, HC);
    alpha_kernel<<<(N_NODES * NH * 64 + 255) / 256, 256, 0, stream>>>(hbuf, a_src2, a_dst2, asb, adb);
    wgt_kernel<<<(N_NODES * NH + 255) / 256, 256, 0, stream>>>(asb, adb, rowptr, srclist, wbuf, denb);
    gather_kernel<<<ngrid, 256, 0, stream>>>(hbuf, wbuf, denb, rowptr, srclist, b2, o2);
    // ---- pool + tail ----
    gpool_kernel<<<NB, HC, 0, stream>>>(o2, gstart, meanb);
    tail_kernel<<<NB, 128, 0, stream>>>(meanb, lw1, lb1, lw2, lb2, out);
}

// Round 4
// 322.185 us; speedup vs baseline: 2.1805x; 1.2665x over previous
//
#include <hip/hip_runtime.h>
#include <hip/hip_bf16.h>
#include <math.h>

#define N_NODES 20000
#define N_EDGES 320000
#define N_EDGES_SL (N_EDGES + N_NODES)
#define NB 32
#define NH 4
#define NC 64
#define HC 256   // NH*NC
#define SCAN_BLOCKS ((N_NODES + 255) / 256)

typedef short s16x8 __attribute__((ext_vector_type(8)));
typedef float f32x4 __attribute__((ext_vector_type(4)));

__device__ __forceinline__ float bf2f(ushort u) {
    union { unsigned int i; float f; } v; v.i = ((unsigned int)u) << 16; return v.f;
}
__device__ __forceinline__ ushort f2bf(float f) {
    union { float f; unsigned int i; } v; v.f = f;
    unsigned int u = v.i;
    unsigned int r = (u + 0x7FFFu + ((u >> 16) & 1u)) >> 16;   // RNE
    return (ushort)r;
}

// ---------------- concat -> bf16: x0[n,0:2]=pos, x0[n,2:64]=x ----------------
__global__ void concat_kernel(const float* __restrict__ x, const float* __restrict__ pos,
                              ushort* __restrict__ x0) {
    int i = blockIdx.x * blockDim.x + threadIdx.x;
    if (i >= N_NODES * 64) return;
    int n = i >> 6, j = i & 63;
    float v = (j < 2) ? pos[n * 2 + j] : x[n * 62 + (j - 2)];
    x0[i] = f2bf(v);
}

// ---------------- W[k][n] -> Wt[n][k] bf16 ----------------
__global__ void tconv_kernel(const float* __restrict__ W, ushort* __restrict__ Wt, int K) {
    int i = blockIdx.x * blockDim.x + threadIdx.x;
    if (i >= 256 * K) return;
    int n = i / K, k = i - n * K;
    Wt[i] = f2bf(W[k * 256 + n]);
}

// ---------------- CSR build ----------------
__global__ void hist_kernel(const int* __restrict__ ei, int* __restrict__ counts) {
    int i = blockIdx.x * blockDim.x + threadIdx.x;
    if (i >= N_EDGES_SL) return;
    int dst = (i < N_EDGES) ? ei[N_EDGES + i] : (i - N_EDGES);
    atomicAdd(&counts[dst], 1);
}

__global__ void scan_block_kernel(const int* __restrict__ counts, int* __restrict__ rowptr,
                                  int* __restrict__ bsums) {
    __shared__ int sm[256];
    int tid = threadIdx.x, blk = blockIdx.x;
    int i = blk * 256 + tid;
    int v = (i < N_NODES) ? counts[i] : 0;
    sm[tid] = v;
    __syncthreads();
#pragma unroll
    for (int off = 1; off < 256; off <<= 1) {
        int t = (tid >= off) ? sm[tid - off] : 0;
        __syncthreads();
        sm[tid] += t;
        __syncthreads();
    }
    if (i < N_NODES) rowptr[i] = sm[tid] - v;
    if (tid == 255) bsums[blk] = sm[255];
}

__global__ void scan_sums_kernel(int* __restrict__ bsums, int* __restrict__ rowptr) {
    __shared__ int sm[128];
    int tid = threadIdx.x;
    int v = (tid < SCAN_BLOCKS) ? bsums[tid] : 0;
    sm[tid] = v;
    __syncthreads();
#pragma unroll
    for (int off = 1; off < 128; off <<= 1) {
        int t = (tid >= off) ? sm[tid - off] : 0;
        __syncthreads();
        sm[tid] += t;
        __syncthreads();
    }
    if (tid < SCAN_BLOCKS) bsums[tid] = sm[tid] - v;
    if (tid == 127) rowptr[N_NODES] = sm[127];
}

__global__ void scan_add_kernel(const int* __restrict__ bsums, int* __restrict__ rowptr) {
    int i = blockIdx.x * blockDim.x + threadIdx.x;
    if (i < N_NODES) rowptr[i] += bsums[blockIdx.x];
}

__global__ void fill_kernel(const int* __restrict__ ei, const int* __restrict__ rowptr,
                            int* __restrict__ fillc, int* __restrict__ srclist) {
    int i = blockIdx.x * blockDim.x + threadIdx.x;
    if (i >= N_EDGES_SL) return;
    int src, dst;
    if (i < N_EDGES) { src = ei[i]; dst = ei[N_EDGES + i]; }
    else             { src = i - N_EDGES; dst = src; }
    int slot = rowptr[dst] + atomicAdd(&fillc[dst], 1);
    srclist[slot] = src;
}

// ---------------- bf16 MFMA GEMM: C[M,256] = A[M,K] @ Bt[n][k]^T ----------------
// 64x64 tile per block (256 thr = 4 waves), K-chunked staging, 16x16x32 mfma.
template<int K, int KC>
__global__ __launch_bounds__(256) void mfma_gemm(const ushort* __restrict__ A,
                                                 const ushort* __restrict__ Bt,
                                                 ushort* __restrict__ C, int M) {
    constexpr int KP = KC + 8;   // +16B pad per row
    __shared__ __align__(16) ushort As[64 * KP];
    __shared__ __align__(16) ushort Bs[64 * KP];
    int tid = threadIdx.x;
    int row0 = blockIdx.y * 64, col0 = blockIdx.x * 64;
    int wave = tid >> 6, lane = tid & 63;
    int mm = lane & 15, quad = lane >> 4;
    f32x4 acc[4] = {};

    for (int kc0 = 0; kc0 < K; kc0 += KC) {
        if (kc0) __syncthreads();
        constexpr int ITER = (64 * KC) / (256 * 8);
#pragma unroll
        for (int it = 0; it < ITER; ++it) {
            int f = it * 2048 + tid * 8;
            int r = f / KC, k = f - r * KC;
            uint4 av = make_uint4(0u, 0u, 0u, 0u);
            if (row0 + r < M) av = *(const uint4*)&A[(size_t)(row0 + r) * K + kc0 + k];
            *(uint4*)&As[r * KP + k] = av;
            uint4 bv = *(const uint4*)&Bt[(size_t)(col0 + r) * K + kc0 + k];
            *(uint4*)&Bs[r * KP + k] = bv;
        }
        __syncthreads();
#pragma unroll
        for (int kt = 0; kt < KC / 32; ++kt) {
            s16x8 a = *(const s16x8*)&As[(wave * 16 + mm) * KP + kt * 32 + quad * 8];
#pragma unroll
            for (int nt = 0; nt < 4; ++nt) {
                s16x8 b = *(const s16x8*)&Bs[(nt * 16 + mm) * KP + kt * 32 + quad * 8];
                acc[nt] = __builtin_amdgcn_mfma_f32_16x16x32_bf16(a, b, acc[nt], 0, 0, 0);
            }
        }
    }
    // C/D layout: col = lane&15, row = quad*4 + reg  [m89-verified]
#pragma unroll
    for (int nt = 0; nt < 4; ++nt)
#pragma unroll
        for (int r = 0; r < 4; ++r) {
            int gr = row0 + wave * 16 + quad * 4 + r;
            if (gr < M) C[(size_t)gr * 256 + col0 + nt * 16 + mm] = f2bf(acc[nt][r]);
        }
}

// ---------------- per-node-head attention dots (h in bf16) ----------------
__global__ __launch_bounds__(256) void alpha_kernel(const ushort* __restrict__ h,
                                                    const float* __restrict__ a_src,
                                                    const float* __restrict__ a_dst,
                                                    float* __restrict__ as_out,
                                                    float* __restrict__ ad_out) {
    int gw = (blockIdx.x * blockDim.x + threadIdx.x) >> 6;
    int lane = threadIdx.x & 63;
    if (gw >= N_NODES * NH) return;
    int n = gw >> 2, hh = gw & 3;
    float hv = bf2f(h[(size_t)n * HC + hh * NC + lane]);
    float s1 = hv * a_src[hh * NC + lane];
    float s2 = hv * a_dst[hh * NC + lane];
#pragma unroll
    for (int off = 32; off; off >>= 1) {
        s1 += __shfl_down(s1, off);
        s2 += __shfl_down(s2, off);
    }
    if (lane == 0) { as_out[n * NH + hh] = s1; ad_out[n * NH + hh] = s2; }
}

// ---------------- softmax weights: one thread per (node, head) ----------------
__global__ __launch_bounds__(256) void wgt_kernel(const float* __restrict__ as_in,
                                                  const float* __restrict__ ad_in,
                                                  const int* __restrict__ rowptr,
                                                  const int* __restrict__ srclist,
                                                  float* __restrict__ w,
                                                  float* __restrict__ denb) {
    int t = blockIdx.x * blockDim.x + threadIdx.x;
    if (t >= N_NODES * NH) return;
    int n = t >> 2, hh = t & 3;
    int start = rowptr[n], end = rowptr[n + 1];
    float adv = ad_in[n * NH + hh];
    float m = -INFINITY;
#pragma unroll 4
    for (int j = start; j < end; ++j) {
        int s = srclist[j];
        float e = as_in[s * NH + hh] + adv;
        e = (e > 0.f) ? e : 0.2f * e;
        m = fmaxf(m, e);
    }
    float den = 0.f;
#pragma unroll 4
    for (int j = start; j < end; ++j) {
        int s = srclist[j];
        float e = as_in[s * NH + hh] + adv;
        e = (e > 0.f) ? e : 0.2f * e;
        float p = __expf(e - m);
        den += p;
        w[j * NH + hh] = p;
    }
    denb[t] = den;
}

// ---------------- weighted gather (h bf16): one wave per node, lane = 4 ch ----------------
__global__ __launch_bounds__(256) void gather_kernel(const ushort* __restrict__ h,
                                                     const float* __restrict__ w,
                                                     const float* __restrict__ denb,
                                                     const int* __restrict__ rowptr,
                                                     const int* __restrict__ srclist,
                                                     const float* __restrict__ bias,
                                                     ushort* __restrict__ out) {
    int node = blockIdx.x * 4 + (threadIdx.x >> 6);
    int lane = threadIdx.x & 63;
    int hh = lane >> 4;
    if (node >= N_NODES) return;
    int start = rowptr[node], end = rowptr[node + 1];
    float4 acc = make_float4(0.f, 0.f, 0.f, 0.f);
#pragma unroll 2
    for (int j = start; j < end; ++j) {
        int s = srclist[j];
        float wv = w[j * NH + hh];
        ushort4 hv = *(const ushort4*)&h[(size_t)s * HC + lane * 4];
        acc.x += wv * bf2f(hv.x); acc.y += wv * bf2f(hv.y);
        acc.z += wv * bf2f(hv.z); acc.w += wv * bf2f(hv.w);
    }
    float inv = 1.0f / (denb[node * NH + hh] + 1e-16f);
    float4 bv = *(const float4*)&bias[lane * 4];
    ushort4 o;
    o.x = f2bf(acc.x * inv + bv.x); o.y = f2bf(acc.y * inv + bv.y);
    o.z = f2bf(acc.z * inv + bv.z); o.w = f2bf(acc.w * inv + bv.w);
    *(ushort4*)&out[(size_t)node * HC + lane * 4] = o;
}

// ---------------- graph boundaries ----------------
__global__ void gbound_kernel(const int* __restrict__ batch, int* __restrict__ gstart) {
    int t = threadIdx.x;
    if (t > NB) return;
    int lo = 0, hi = N_NODES;
    while (lo < hi) {
        int mid = (lo + hi) >> 1;
        if (batch[mid] < t) lo = mid + 1; else hi = mid;
    }
    gstart[t] = lo;
}

// ---------------- mean pool (o2 bf16): one block per graph ----------------
__global__ __launch_bounds__(256) void gpool_kernel(const ushort* __restrict__ o2,
                                                    const int* __restrict__ gstart,
                                                    float* __restrict__ mean) {
    int b = blockIdx.x, c = threadIdx.x;
    int s = gstart[b], e = gstart[b + 1];
    int cnt = e - s;
    float s0 = 0.f, s1 = 0.f, s2 = 0.f, s3 = 0.f;
    int n = s;
    for (; n + 3 < e; n += 4) {
        s0 += bf2f(o2[(size_t)(n + 0) * HC + c]);
        s1 += bf2f(o2[(size_t)(n + 1) * HC + c]);
        s2 += bf2f(o2[(size_t)(n + 2) * HC + c]);
        s3 += bf2f(o2[(size_t)(n + 3) * HC + c]);
    }
    for (; n < e; ++n) s0 += bf2f(o2[(size_t)n * HC + c]);
    float inv = 1.0f / (float)max(cnt, 1);
    mean[b * HC + c] = (s0 + s1 + s2 + s3) * inv;
}

// ---------------- MLP tail ----------------
__global__ __launch_bounds__(128) void tail_kernel(const float* __restrict__ mean,
                                                   const float* __restrict__ lw1,
                                                   const float* __restrict__ lb1,
                                                   const float* __restrict__ lw2,
                                                   const float* __restrict__ lb2,
                                                   float* __restrict__ out) {
    __shared__ float pm[HC];
    __shared__ float hid[128];
    int b = blockIdx.x, t = threadIdx.x;
    pm[t] = mean[b * HC + t];
    pm[t + 128] = mean[b * HC + t + 128];
    __syncthreads();
    float s = lb1[t];
    for (int c = 0; c < HC; ++c) s += pm[c] * lw1[c * 128 + t];
    hid[t] = fmaxf(s, 0.f);
    __syncthreads();
    if (t < 10) {
        float s2 = lb2[t];
        for (int k = 0; k < 128; ++k) s2 += hid[k] * lw2[k * 10 + t];
        out[b * 10 + t] = fmaxf(s2, 0.f);
    }
}

extern "C" void kernel_launch(void* const* d_in, const int* in_sizes, int n_in,
                              void* d_out, int out_size, void* d_ws, size_t ws_size,
                              hipStream_t stream) {
    const float* x      = (const float*)d_in[0];
    const float* pos    = (const float*)d_in[1];
    const int*   ei     = (const int*)d_in[2];
    const int*   batch  = (const int*)d_in[3];
    const float* W1     = (const float*)d_in[4];
    const float* a_src1 = (const float*)d_in[5];
    const float* a_dst1 = (const float*)d_in[6];
    const float* b1     = (const float*)d_in[7];
    const float* W2     = (const float*)d_in[8];
    const float* a_src2 = (const float*)d_in[9];
    const float* a_dst2 = (const float*)d_in[10];
    const float* b2     = (const float*)d_in[11];
    const float* lw1    = (const float*)d_in[12];
    const float* lb1    = (const float*)d_in[13];
    const float* lw2    = (const float*)d_in[14];
    const float* lb2    = (const float*)d_in[15];
    float* out = (float*)d_out;

    char* ws = (char*)d_ws;
    size_t off = 0;
    auto alloc = [&](size_t bytes) -> void* {
        void* p = ws + off;
        off = (off + bytes + 255) & ~(size_t)255;
        return p;
    };
    int*    counts  = (int*)alloc(N_NODES * 4);
    int*    fillc   = (int*)alloc(N_NODES * 4);
    size_t zero_bytes = off;
    int*    rowptr  = (int*)alloc((N_NODES + 1) * 4);
    int*    bsums   = (int*)alloc(SCAN_BLOCKS * 4);
    int*    srclist = (int*)alloc((size_t)N_EDGES_SL * 4);
    int*    gstart  = (int*)alloc((NB + 1) * 4);
    ushort* x0      = (ushort*)alloc((size_t)N_NODES * 64 * 2);
    ushort* Wt1     = (ushort*)alloc(256 * 64 * 2);
    ushort* Wt2     = (ushort*)alloc(256 * 256 * 2);
    ushort* hbuf    = (ushort*)alloc((size_t)N_NODES * HC * 2);
    ushort* o1      = (ushort*)alloc((size_t)N_NODES * HC * 2);  // reused as o2
    float*  asb     = (float*)alloc((size_t)N_NODES * NH * 4);
    float*  adb     = (float*)alloc((size_t)N_NODES * NH * 4);
    float*  wbuf    = (float*)alloc((size_t)N_EDGES_SL * NH * 4);
    float*  denb    = (float*)alloc((size_t)N_NODES * NH * 4);
    float*  meanb   = (float*)alloc(NB * HC * 4);
    ushort* o2 = o1;

    hipMemsetAsync(d_ws, 0, zero_bytes, stream);

    concat_kernel<<<(N_NODES * 64 + 255) / 256, 256, 0, stream>>>(x, pos, x0);
    tconv_kernel<<<(256 * 64 + 255) / 256, 256, 0, stream>>>(W1, Wt1, 64);
    tconv_kernel<<<(256 * 256 + 255) / 256, 256, 0, stream>>>(W2, Wt2, 256);
    hist_kernel<<<(N_EDGES_SL + 255) / 256, 256, 0, stream>>>(ei, counts);
    scan_block_kernel<<<SCAN_BLOCKS, 256, 0, stream>>>(counts, rowptr, bsums);
    scan_sums_kernel<<<1, 128, 0, stream>>>(bsums, rowptr);
    scan_add_kernel<<<SCAN_BLOCKS, 256, 0, stream>>>(bsums, rowptr);
    fill_kernel<<<(N_EDGES_SL + 255) / 256, 256, 0, stream>>>(ei, rowptr, fillc, srclist);
    gbound_kernel<<<1, 64, 0, stream>>>(batch, gstart);

    dim3 ggrid(4, (N_NODES + 63) / 64);
    int ngrid = (N_NODES + 3) / 4;
    // ---- layer 1 ----
    mfma_gemm<64, 64><<<ggrid, 256, 0, stream>>>(x0, Wt1, hbuf, N_NODES);
    alpha_kernel<<<(N_NODES * NH * 64 + 255) / 256, 256, 0, stream>>>(hbuf, a_src1, a_dst1, asb, adb);
    wgt_kernel<<<(N_NODES * NH + 255) / 256, 256, 0, stream>>>(asb, adb, rowptr, srclist, wbuf, denb);
    gather_kernel<<<ngrid, 256, 0, stream>>>(hbuf, wbuf, denb, rowptr, srclist, b1, o1);
    // ---- layer 2 ----
    mfma_gemm<256, 128><<<ggrid, 256, 0, stream>>>(o1, Wt2, hbuf, N_NODES);
    alpha_kernel<<<(N_NODES * NH * 64 + 255) / 256, 256, 0, stream>>>(hbuf, a_src2, a_dst2, asb, adb);
    wgt_kernel<<<(N_NODES * NH + 255) / 256, 256, 0, stream>>>(asb, adb, rowptr, srclist, wbuf, denb);
    gather_kernel<<<ngrid, 256, 0, stream>>>(hbuf, wbuf, denb, rowptr, srclist, b2, o2);
    // ---- pool + tail ----
    gpool_kernel<<<NB, HC, 0, stream>>>(o2, gstart, meanb);
    tail_kernel<<<NB, 128, 0, stream>>>(meanb, lw1, lb1, lw2, lb2, out);
}

// Round 5
// 272.715 us; speedup vs baseline: 2.5760x; 1.1814x over previous
//
#include <hip/hip_runtime.h>
#include <hip/hip_bf16.h>
#include <math.h>

#define N_NODES 20000
#define N_EDGES 320000
#define N_EDGES_SL (N_EDGES + N_NODES)
#define NB 32
#define NH 4
#define NC 64
#define HC 256   // NH*NC
#define SCAN_BLOCKS ((N_NODES + 255) / 256)
#define POOL_CH 20

typedef short s16x8 __attribute__((ext_vector_type(8)));
typedef float f32x4 __attribute__((ext_vector_type(4)));

__device__ __forceinline__ float bf2f(ushort u) {
    union { unsigned int i; float f; } v; v.i = ((unsigned int)u) << 16; return v.f;
}
__device__ __forceinline__ ushort f2bf(float f) {
    union { float f; unsigned int i; } v; v.f = f;
    unsigned int u = v.i;
    unsigned int r = (u + 0x7FFFu + ((u >> 16) & 1u)) >> 16;   // RNE
    return (ushort)r;
}

// ---------------- concat -> bf16 ----------------
__global__ void concat_kernel(const float* __restrict__ x, const float* __restrict__ pos,
                              ushort* __restrict__ x0) {
    int i = blockIdx.x * blockDim.x + threadIdx.x;
    if (i >= N_NODES * 64) return;
    int n = i >> 6, j = i & 63;
    float v = (j < 2) ? pos[n * 2 + j] : x[n * 62 + (j - 2)];
    x0[i] = f2bf(v);
}

// ---------------- W[k][n] -> Wt[n][k] bf16 ----------------
__global__ void tconv_kernel(const float* __restrict__ W, ushort* __restrict__ Wt, int K) {
    int i = blockIdx.x * blockDim.x + threadIdx.x;
    if (i >= 256 * K) return;
    int n = i / K, k = i - n * K;
    Wt[i] = f2bf(W[k * 256 + n]);
}

// ---------------- CSR build ----------------
__global__ void hist_kernel(const int* __restrict__ ei, int* __restrict__ counts) {
    int i = blockIdx.x * blockDim.x + threadIdx.x;
    if (i >= N_EDGES_SL) return;
    int dst = (i < N_EDGES) ? ei[N_EDGES + i] : (i - N_EDGES);
    atomicAdd(&counts[dst], 1);
}

__global__ void scan_block_kernel(const int* __restrict__ counts, int* __restrict__ rowptr,
                                  int* __restrict__ bsums) {
    __shared__ int sm[256];
    int tid = threadIdx.x, blk = blockIdx.x;
    int i = blk * 256 + tid;
    int v = (i < N_NODES) ? counts[i] : 0;
    sm[tid] = v;
    __syncthreads();
#pragma unroll
    for (int off = 1; off < 256; off <<= 1) {
        int t = (tid >= off) ? sm[tid - off] : 0;
        __syncthreads();
        sm[tid] += t;
        __syncthreads();
    }
    if (i < N_NODES) rowptr[i] = sm[tid] - v;
    if (tid == 255) bsums[blk] = sm[255];
}

__global__ void scan_sums_kernel(int* __restrict__ bsums, int* __restrict__ rowptr) {
    __shared__ int sm[128];
    int tid = threadIdx.x;
    int v = (tid < SCAN_BLOCKS) ? bsums[tid] : 0;
    sm[tid] = v;
    __syncthreads();
#pragma unroll
    for (int off = 1; off < 128; off <<= 1) {
        int t = (tid >= off) ? sm[tid - off] : 0;
        __syncthreads();
        sm[tid] += t;
        __syncthreads();
    }
    if (tid < SCAN_BLOCKS) bsums[tid] = sm[tid] - v;
    if (tid == 127) rowptr[N_NODES] = sm[127];
}

__global__ void scan_add_kernel(const int* __restrict__ bsums, int* __restrict__ rowptr) {
    int i = blockIdx.x * blockDim.x + threadIdx.x;
    if (i < N_NODES) rowptr[i] += bsums[blockIdx.x];
}

__global__ void fill_kernel(const int* __restrict__ ei, const int* __restrict__ rowptr,
                            int* __restrict__ fillc, int* __restrict__ srclist) {
    int i = blockIdx.x * blockDim.x + threadIdx.x;
    if (i >= N_EDGES_SL) return;
    int src, dst;
    if (i < N_EDGES) { src = ei[i]; dst = ei[N_EDGES + i]; }
    else             { src = i - N_EDGES; dst = src; }
    int slot = rowptr[dst] + atomicAdd(&fillc[dst], 1);
    srclist[slot] = src;
}

// ---------------- bf16 MFMA GEMM: C[M,256] = A[M,K] @ Bt[n][k]^T ----------------
template<int K, int KC>
__global__ __launch_bounds__(256) void mfma_gemm(const ushort* __restrict__ A,
                                                 const ushort* __restrict__ Bt,
                                                 ushort* __restrict__ C, int M) {
    constexpr int KP = KC + 8;
    __shared__ __align__(16) ushort As[64 * KP];
    __shared__ __align__(16) ushort Bs[64 * KP];
    int tid = threadIdx.x;
    int row0 = blockIdx.y * 64, col0 = blockIdx.x * 64;
    int wave = tid >> 6, lane = tid & 63;
    int mm = lane & 15, quad = lane >> 4;
    f32x4 acc[4] = {};

    for (int kc0 = 0; kc0 < K; kc0 += KC) {
        if (kc0) __syncthreads();
        constexpr int ITER = (64 * KC) / (256 * 8);
#pragma unroll
        for (int it = 0; it < ITER; ++it) {
            int f = it * 2048 + tid * 8;
            int r = f / KC, k = f - r * KC;
            uint4 av = make_uint4(0u, 0u, 0u, 0u);
            if (row0 + r < M) av = *(const uint4*)&A[(size_t)(row0 + r) * K + kc0 + k];
            *(uint4*)&As[r * KP + k] = av;
            uint4 bv = *(const uint4*)&Bt[(size_t)(col0 + r) * K + kc0 + k];
            *(uint4*)&Bs[r * KP + k] = bv;
        }
        __syncthreads();
#pragma unroll
        for (int kt = 0; kt < KC / 32; ++kt) {
            s16x8 a = *(const s16x8*)&As[(wave * 16 + mm) * KP + kt * 32 + quad * 8];
#pragma unroll
            for (int nt = 0; nt < 4; ++nt) {
                s16x8 b = *(const s16x8*)&Bs[(nt * 16 + mm) * KP + kt * 32 + quad * 8];
                acc[nt] = __builtin_amdgcn_mfma_f32_16x16x32_bf16(a, b, acc[nt], 0, 0, 0);
            }
        }
    }
#pragma unroll
    for (int nt = 0; nt < 4; ++nt)
#pragma unroll
        for (int r = 0; r < 4; ++r) {
            int gr = row0 + wave * 16 + quad * 4 + r;
            if (gr < M) C[(size_t)gr * 256 + col0 + nt * 16 + mm] = f2bf(acc[nt][r]);
        }
}

// ---------------- attention dots: one wave per node, ushort4/lane ----------------
__global__ __launch_bounds__(256) void alpha_kernel(const ushort* __restrict__ h,
                                                    const float* __restrict__ a_src,
                                                    const float* __restrict__ a_dst,
                                                    float* __restrict__ as_out,
                                                    float* __restrict__ ad_out) {
    int n = blockIdx.x * 4 + (threadIdx.x >> 6);
    int lane = threadIdx.x & 63;
    if (n >= N_NODES) return;
    int hh = lane >> 4;                         // 16 lanes x 4ch = 64ch = 1 head
    ushort4 hv = *(const ushort4*)&h[(size_t)n * HC + lane * 4];
    const float* asrc = &a_src[hh * NC + (lane & 15) * 4];
    const float* adst = &a_dst[hh * NC + (lane & 15) * 4];
    float h0 = bf2f(hv.x), h1 = bf2f(hv.y), h2 = bf2f(hv.z), h3 = bf2f(hv.w);
    float s1 = h0 * asrc[0] + h1 * asrc[1] + h2 * asrc[2] + h3 * asrc[3];
    float s2 = h0 * adst[0] + h1 * adst[1] + h2 * adst[2] + h3 * adst[3];
#pragma unroll
    for (int off = 8; off; off >>= 1) {
        s1 += __shfl_down(s1, off);
        s2 += __shfl_down(s2, off);
    }
    if ((lane & 15) == 0) {
        as_out[n * NH + hh] = s1;
        ad_out[n * NH + hh] = s2;
    }
}

// ---------------- softmax weights: one thread per (node, head) ----------------
__global__ __launch_bounds__(256) void wgt_kernel(const float* __restrict__ as_in,
                                                  const float* __restrict__ ad_in,
                                                  const int* __restrict__ rowptr,
                                                  const int* __restrict__ srclist,
                                                  float* __restrict__ w,
                                                  float* __restrict__ denb) {
    int t = blockIdx.x * blockDim.x + threadIdx.x;
    if (t >= N_NODES * NH) return;
    int n = t >> 2, hh = t & 3;
    int start = rowptr[n], end = rowptr[n + 1];
    float adv = ad_in[n * NH + hh];
    float m = -INFINITY;
#pragma unroll 4
    for (int j = start; j < end; ++j) {
        int s = srclist[j];
        float e = as_in[s * NH + hh] + adv;
        e = (e > 0.f) ? e : 0.2f * e;
        m = fmaxf(m, e);
    }
    float den = 0.f;
#pragma unroll 4
    for (int j = start; j < end; ++j) {
        int s = srclist[j];
        float e = as_in[s * NH + hh] + adv;
        e = (e > 0.f) ? e : 0.2f * e;
        float p = __expf(e - m);
        den += p;
        w[j * NH + hh] = p;
    }
    denb[t] = den;
}

// ---------------- weighted gather: one wave per node ----------------
__global__ __launch_bounds__(256) void gather_kernel(const ushort* __restrict__ h,
                                                     const float* __restrict__ w,
                                                     const float* __restrict__ denb,
                                                     const int* __restrict__ rowptr,
                                                     const int* __restrict__ srclist,
                                                     const float* __restrict__ bias,
                                                     ushort* __restrict__ out) {
    int node = blockIdx.x * 4 + (threadIdx.x >> 6);
    int lane = threadIdx.x & 63;
    int hh = lane >> 4;
    if (node >= N_NODES) return;
    int start = rowptr[node], end = rowptr[node + 1];
    float4 acc = make_float4(0.f, 0.f, 0.f, 0.f);
#pragma unroll 2
    for (int j = start; j < end; ++j) {
        int s = srclist[j];
        float wv = w[j * NH + hh];
        ushort4 hv = *(const ushort4*)&h[(size_t)s * HC + lane * 4];
        acc.x += wv * bf2f(hv.x); acc.y += wv * bf2f(hv.y);
        acc.z += wv * bf2f(hv.z); acc.w += wv * bf2f(hv.w);
    }
    float inv = 1.0f / (denb[node * NH + hh] + 1e-16f);
    float4 bv = *(const float4*)&bias[lane * 4];
    ushort4 o;
    o.x = f2bf(acc.x * inv + bv.x); o.y = f2bf(acc.y * inv + bv.y);
    o.z = f2bf(acc.z * inv + bv.z); o.w = f2bf(acc.w * inv + bv.w);
    *(ushort4*)&out[(size_t)node * HC + lane * 4] = o;
}

// ---------------- graph boundaries ----------------
__global__ void gbound_kernel(const int* __restrict__ batch, int* __restrict__ gstart) {
    int t = threadIdx.x;
    if (t > NB) return;
    int lo = 0, hi = N_NODES;
    while (lo < hi) {
        int mid = (lo + hi) >> 1;
        if (batch[mid] < t) lo = mid + 1; else hi = mid;
    }
    gstart[t] = lo;
}

// ---------------- mean pool stage 1: 32 graphs x POOL_CH chunks, fp32 atomics ----------------
__global__ __launch_bounds__(256) void gpool_kernel(const ushort* __restrict__ o2,
                                                    const int* __restrict__ gstart,
                                                    float* __restrict__ poolsum) {
    int b = blockIdx.x / POOL_CH, chunk = blockIdx.x % POOL_CH;
    int c = threadIdx.x;
    int s = gstart[b], e = gstart[b + 1];
    int cnt = e - s;
    int per = (cnt + POOL_CH - 1) / POOL_CH;
    int ns = s + chunk * per;
    int ne = min(ns + per, e);
    if (ns >= ne) return;
    float acc = 0.f;
    for (int n = ns; n < ne; ++n) acc += bf2f(o2[(size_t)n * HC + c]);
    atomicAdd(&poolsum[b * HC + c], acc);
}

// ---------------- MLP tail (divides poolsum by count) ----------------
__global__ __launch_bounds__(128) void tail_kernel(const float* __restrict__ poolsum,
                                                   const int* __restrict__ gstart,
                                                   const float* __restrict__ lw1,
                                                   const float* __restrict__ lb1,
                                                   const float* __restrict__ lw2,
                                                   const float* __restrict__ lb2,
                                                   float* __restrict__ out) {
    __shared__ float pm[HC];
    __shared__ float hid[128];
    int b = blockIdx.x, t = threadIdx.x;
    int cnt = gstart[b + 1] - gstart[b];
    float inv = 1.0f / (float)max(cnt, 1);
    pm[t] = poolsum[b * HC + t] * inv;
    pm[t + 128] = poolsum[b * HC + t + 128] * inv;
    __syncthreads();
    float s = lb1[t];
    for (int c = 0; c < HC; ++c) s += pm[c] * lw1[c * 128 + t];
    hid[t] = fmaxf(s, 0.f);
    __syncthreads();
    if (t < 10) {
        float s2 = lb2[t];
        for (int k = 0; k < 128; ++k) s2 += hid[k] * lw2[k * 10 + t];
        out[b * 10 + t] = fmaxf(s2, 0.f);
    }
}

extern "C" void kernel_launch(void* const* d_in, const int* in_sizes, int n_in,
                              void* d_out, int out_size, void* d_ws, size_t ws_size,
                              hipStream_t stream) {
    const float* x      = (const float*)d_in[0];
    const float* pos    = (const float*)d_in[1];
    const int*   ei     = (const int*)d_in[2];
    const int*   batch  = (const int*)d_in[3];
    const float* W1     = (const float*)d_in[4];
    const float* a_src1 = (const float*)d_in[5];
    const float* a_dst1 = (const float*)d_in[6];
    const float* b1     = (const float*)d_in[7];
    const float* W2     = (const float*)d_in[8];
    const float* a_src2 = (const float*)d_in[9];
    const float* a_dst2 = (const float*)d_in[10];
    const float* b2     = (const float*)d_in[11];
    const float* lw1    = (const float*)d_in[12];
    const float* lb1    = (const float*)d_in[13];
    const float* lw2    = (const float*)d_in[14];
    const float* lb2    = (const float*)d_in[15];
    float* out = (float*)d_out;

    char* ws = (char*)d_ws;
    size_t off = 0;
    auto alloc = [&](size_t bytes) -> void* {
        void* p = ws + off;
        off = (off + bytes + 255) & ~(size_t)255;
        return p;
    };
    int*    counts  = (int*)alloc(N_NODES * 4);
    int*    fillc   = (int*)alloc(N_NODES * 4);
    float*  poolsum = (float*)alloc(NB * HC * 4);
    size_t zero_bytes = off;
    int*    rowptr  = (int*)alloc((N_NODES + 1) * 4);
    int*    bsums   = (int*)alloc(SCAN_BLOCKS * 4);
    int*    srclist = (int*)alloc((size_t)N_EDGES_SL * 4);
    int*    gstart  = (int*)alloc((NB + 1) * 4);
    ushort* x0      = (ushort*)alloc((size_t)N_NODES * 64 * 2);
    ushort* Wt1     = (ushort*)alloc(256 * 64 * 2);
    ushort* Wt2     = (ushort*)alloc(256 * 256 * 2);
    ushort* hbuf    = (ushort*)alloc((size_t)N_NODES * HC * 2);
    ushort* o1      = (ushort*)alloc((size_t)N_NODES * HC * 2);  // reused as o2
    float*  asb     = (float*)alloc((size_t)N_NODES * NH * 4);
    float*  adb     = (float*)alloc((size_t)N_NODES * NH * 4);
    float*  wbuf    = (float*)alloc((size_t)N_EDGES_SL * NH * 4);
    float*  denb    = (float*)alloc((size_t)N_NODES * NH * 4);
    ushort* o2 = o1;

    hipMemsetAsync(d_ws, 0, zero_bytes, stream);

    concat_kernel<<<(N_NODES * 64 + 255) / 256, 256, 0, stream>>>(x, pos, x0);
    tconv_kernel<<<(256 * 64 + 255) / 256, 256, 0, stream>>>(W1, Wt1, 64);
    tconv_kernel<<<(256 * 256 + 255) / 256, 256, 0, stream>>>(W2, Wt2, 256);
    hist_kernel<<<(N_EDGES_SL + 255) / 256, 256, 0, stream>>>(ei, counts);
    scan_block_kernel<<<SCAN_BLOCKS, 256, 0, stream>>>(counts, rowptr, bsums);
    scan_sums_kernel<<<1, 128, 0, stream>>>(bsums, rowptr);
    scan_add_kernel<<<SCAN_BLOCKS, 256, 0, stream>>>(bsums, rowptr);
    fill_kernel<<<(N_EDGES_SL + 255) / 256, 256, 0, stream>>>(ei, rowptr, fillc, srclist);
    gbound_kernel<<<1, 64, 0, stream>>>(batch, gstart);

    dim3 ggrid(4, (N_NODES + 63) / 64);
    int ngrid = (N_NODES + 3) / 4;
    // ---- layer 1 ----
    mfma_gemm<64, 64><<<ggrid, 256, 0, stream>>>(x0, Wt1, hbuf, N_NODES);
    alpha_kernel<<<ngrid, 256, 0, stream>>>(hbuf, a_src1, a_dst1, asb, adb);
    wgt_kernel<<<(N_NODES * NH + 255) / 256, 256, 0, stream>>>(asb, adb, rowptr, srclist, wbuf, denb);
    gather_kernel<<<ngrid, 256, 0, stream>>>(hbuf, wbuf, denb, rowptr, srclist, b1, o1);
    // ---- layer 2 ----
    mfma_gemm<256, 128><<<ggrid, 256, 0, stream>>>(o1, Wt2, hbuf, N_NODES);
    alpha_kernel<<<ngrid, 256, 0, stream>>>(hbuf, a_src2, a_dst2, asb, adb);
    wgt_kernel<<<(N_NODES * NH + 255) / 256, 256, 0, stream>>>(asb, adb, rowptr, srclist, wbuf, denb);
    gather_kernel<<<ngrid, 256, 0, stream>>>(hbuf, wbuf, denb, rowptr, srclist, b2, o2);
    // ---- pool + tail ----
    gpool_kernel<<<NB * POOL_CH, HC, 0, stream>>>(o2, gstart, poolsum);
    tail_kernel<<<NB, 128, 0, stream>>>(poolsum, gstart, lw1, lb1, lw2, lb2, out);
}